// Round 4
// baseline (146.022 us; speedup 1.0000x reference)
//
#include <hip/hip_runtime.h>

#define DEG 32
#define HID 32
#define CIN 8

typedef float v2f __attribute__((ext_vector_type(2)));

// gelu(x) = x - x * rcp(1 + exp2( x*(A + B*x^2) ))   [jax tanh-approx, refactored]
#define GELU_A ((float)(2.0 * 1.4426950408889634 * 0.7978845608028654))
#define GELU_B ((float)(2.0 * 1.4426950408889634 * 0.7978845608028654 * 0.044715))

__device__ __forceinline__ unsigned f2bf(float f) {   // fp32 -> bf16 (RNE)
    unsigned b = __float_as_uint(f);
    return (b + 0x7fffu + ((b >> 16) & 1u)) >> 16;
}

// Phase 1: u16[n][h] = bf16( x[n] @ W1[:8][h] ).  Thread per (node, 8 channels):
// packs 8 bf16 into a uint4 store (row = 64B = one cache line).
__global__ __launch_bounds__(256) void precompute_u16(
    const float* __restrict__ x, const float* __restrict__ W1,
    unsigned* __restrict__ u16, int N) {
    int tid = blockIdx.x * 256 + threadIdx.x;
    if (tid >= N * 4) return;
    int n = tid >> 2;
    int q = tid & 3;                        // channels q*8 .. q*8+7
    const float4* xp = (const float4*)(x + (size_t)n * CIN);
    float4 a = xp[0], b = xp[1];
    float xv[8] = {a.x, a.y, a.z, a.w, b.x, b.y, b.z, b.w};
    float s[8];
#pragma unroll
    for (int c = 0; c < 8; ++c) s[c] = 0.f;
#pragma unroll
    for (int k = 0; k < 8; ++k) {
        float4 w0 = *(const float4*)(W1 + k * HID + q * 8);
        float4 w1 = *(const float4*)(W1 + k * HID + q * 8 + 4);
        s[0] = fmaf(xv[k], w0.x, s[0]); s[1] = fmaf(xv[k], w0.y, s[1]);
        s[2] = fmaf(xv[k], w0.z, s[2]); s[3] = fmaf(xv[k], w0.w, s[3]);
        s[4] = fmaf(xv[k], w1.x, s[4]); s[5] = fmaf(xv[k], w1.y, s[5]);
        s[6] = fmaf(xv[k], w1.z, s[6]); s[7] = fmaf(xv[k], w1.w, s[7]);
    }
    uint4 o;
    o.x = f2bf(s[0]) | (f2bf(s[1]) << 16);
    o.y = f2bf(s[2]) | (f2bf(s[3]) << 16);
    o.z = f2bf(s[4]) | (f2bf(s[5]) << 16);
    o.w = f2bf(s[6]) | (f2bf(s[7]) << 16);
    *(uint4*)(u16 + (size_t)n * 16 + q * 4) = o;
}

// Phase 2: ONE WAVE PER NODE. lane = eg*16 + c2:  eg = edge-group (4 groups x 8
// edges), c2 = channel-pair (channels 2c2, 2c2+1) -> packed-fp32 gelu on 2 ch.
//   v_i = b1 + x_i @ W1[8:]                              (preamble, packed)
//   g   = sum_j w_j * gelu(bf16_u_j + v_i)               (8-iter loop, 8 loads batched)
//   out = (g @ W2 + (sum_j w_j)*b2) / 32                 (hoisted 2nd linear)
__global__ __launch_bounds__(256, 8) void git_main2(
    const unsigned* __restrict__ u16, const float* __restrict__ x,
    const float* __restrict__ wgt, const float* __restrict__ W1,
    const float* __restrict__ b1, const float* __restrict__ W2,
    const float* __restrict__ b2, const int* __restrict__ nbr,
    float* __restrict__ out, int N) {
    __shared__ float sW2[HID * HID];
    __shared__ float sb2[HID];

    int t = threadIdx.x;
#pragma unroll
    for (int i = 0; i < 4; ++i) sW2[t + i * 256] = W2[t + i * 256];
    if (t < HID) sb2[t] = b2[t];
    __syncthreads();

    int lane = t & 63;
    int c2   = lane & 15;                 // channel pair: channels 2c2, 2c2+1
    int eg   = lane >> 4;                 // edge group 0..3 (8 edges each)
    int node = blockIdx.x * 4 + (t >> 6);
    bool valid = node < N;
    int nc = valid ? node : (N - 1);

    // lanes 0..31 (dup in upper half) hold edge (lane&31)'s byte-offset + weight
    int   j_own = nbr[nc * DEG + (lane & 31)];     // coalesced
    int   off_l = j_own << 6;                      // bf16 row = 64 bytes
    float w_own = wgt[j_own];                      // 400KB table, cache-hot

    // ws = sum of the 32 neighbor weights (each half holds all 32 -> butterfly)
    float ws = w_own;
    ws += __shfl_xor(ws, 1);  ws += __shfl_xor(ws, 2);
    ws += __shfl_xor(ws, 4);  ws += __shfl_xor(ws, 8);
    ws += __shfl_xor(ws, 16);

    // v = b1 + x_i @ W1[8:16] for this lane's 2 channels (packed)
    const float4* xip = (const float4*)(x + (size_t)nc * CIN);
    float4 xa = xip[0], xb = xip[1];
    float xs[8] = {xa.x, xa.y, xa.z, xa.w, xb.x, xb.y, xb.z, xb.w};
    v2f vb = *(const v2f*)(b1 + c2 * 2);
#pragma unroll
    for (int k = 0; k < 8; ++k) {
        v2f wcol = *(const v2f*)(W1 + (8 + k) * HID + c2 * 2);
        vb += xs[k] * wcol;
    }

    // ---- gather loop: batch all 8 loads, then compute ----
    const char* ub = (const char*)u16;
    unsigned bits[8];
    float    wes[8];
#pragma unroll
    for (int it = 0; it < 8; ++it) {
        int src = eg * 8 + it;                       // this group's edge
        int off_e = __shfl(off_l, src);
        wes[it]   = __shfl(w_own, src);
        bits[it]  = *(const unsigned*)(ub + (unsigned)(off_e + c2 * 4));
    }

    const v2f As = {GELU_A, GELU_B};   // .x=A, .y=B (kept in 1 reg-pair)
    v2f g = {0.f, 0.f};
#pragma unroll
    for (int it = 0; it < 8; ++it) {
        unsigned bb = bits[it];
        v2f uf;
        uf.x = __uint_as_float(bb << 16);
        uf.y = __uint_as_float(bb & 0xffff0000u);
        v2f tt = uf + vb;
        v2f x2 = tt * tt;
        v2f zz = tt * (x2 * As.y + As.x);
        v2f ee;
        ee.x = __builtin_amdgcn_exp2f(zz.x);
        ee.y = __builtin_amdgcn_exp2f(zz.y);
        v2f dd = ee + 1.0f;
        v2f rr;
        rr.x = __builtin_amdgcn_rcpf(dd.x);
        rr.y = __builtin_amdgcn_rcpf(dd.y);
        v2f gl = tt - tt * rr;          // gelu(tt); correct limits at +/-inf
        v2f we = {wes[it], wes[it]};
        g += we * gl;
    }

    // reduce g across the 4 edge groups (lanes differing in bits 4,5)
    g.x += __shfl_xor(g.x, 16);  g.y += __shfl_xor(g.y, 16);
    g.x += __shfl_xor(g.x, 32);  g.y += __shfl_xor(g.y, 32);

    // second linear, hoisted per node: acc[o] = sum_h g[h] * W2[h][o]
    // h-range split 4 ways across edge groups; channel h lives in lane h>>1.
    v2f acc = {0.f, 0.f};
#pragma unroll
    for (int hh = 0; hh < 8; ++hh) {
        int h = eg * 8 + hh;
        float gh = (hh & 1) ? __shfl(g.y, eg * 4 + (hh >> 1))
                            : __shfl(g.x, eg * 4 + (hh >> 1));
        v2f wrow = *(const v2f*)(sW2 + h * HID + c2 * 2);
        acc += gh * wrow;
    }
    acc.x += __shfl_xor(acc.x, 16);  acc.y += __shfl_xor(acc.y, 16);
    acc.x += __shfl_xor(acc.x, 32);  acc.y += __shfl_xor(acc.y, 32);

    if (valid && eg == 0) {
        v2f bb2 = *(const v2f*)(sb2 + c2 * 2);
        v2f res = (acc + ws * bb2) * (1.0f / DEG);
        *(v2f*)(out + (size_t)node * HID + c2 * 2) = res;
    }
}

// Fallback if d_ws can't hold u16 (needs N*64 bytes): round-2 single kernel.
__global__ __launch_bounds__(256) void fused_fallback(
    const float* __restrict__ x, const float* __restrict__ wgt,
    const float* __restrict__ W1, const float* __restrict__ b1,
    const float* __restrict__ W2, const float* __restrict__ b2,
    const int* __restrict__ nbr, float* __restrict__ out, int N) {
    __shared__ float sW2[HID * HID];
    __shared__ float sb2[HID];
    __shared__ int2  sp[8 * DEG];
    int t = threadIdx.x;
#pragma unroll
    for (int i = 0; i < 4; ++i) sW2[t + i * 256] = W2[t + i * 256];
    if (t < HID) sb2[t] = b2[t];
    int slot = t >> 5, hid = t & 31;
    int node = blockIdx.x * 8 + slot;
    bool valid = node < N;
    int nc = valid ? node : (N - 1);
    int   j_own = nbr[nc * DEG + hid];
    float w_own = wgt[j_own];
    sp[slot * DEG + hid] = make_int2(j_own * (CIN * 4), __float_as_int(w_own));
    const float4* xip = (const float4*)(x + (size_t)nc * CIN);
    float4 xa = xip[0], xb = xip[1];
    float w1t[8];
#pragma unroll
    for (int k = 0; k < 8; ++k) w1t[k] = W1[k * HID + hid];
    float vb = b1[hid];
    vb = fmaf(xa.x, W1[ 8 * HID + hid], vb);
    vb = fmaf(xa.y, W1[ 9 * HID + hid], vb);
    vb = fmaf(xa.z, W1[10 * HID + hid], vb);
    vb = fmaf(xa.w, W1[11 * HID + hid], vb);
    vb = fmaf(xb.x, W1[12 * HID + hid], vb);
    vb = fmaf(xb.y, W1[13 * HID + hid], vb);
    vb = fmaf(xb.z, W1[14 * HID + hid], vb);
    vb = fmaf(xb.w, W1[15 * HID + hid], vb);
    float ws = w_own;
    ws += __shfl_xor(ws, 1);  ws += __shfl_xor(ws, 2);
    ws += __shfl_xor(ws, 4);  ws += __shfl_xor(ws, 8);
    ws += __shfl_xor(ws, 16);
    __syncthreads();
    const char* xbytes = (const char*)x;
    const int2* myp = &sp[slot * DEG];
    float g = 0.f;
#pragma unroll 8
    for (int e = 0; e < DEG; ++e) {
        int2  p  = myp[e];
        float wj = __int_as_float(p.y);
        const float4* xjp = (const float4*)(xbytes + (unsigned)p.x);
        float4 a = xjp[0], b = xjp[1];
        float tin = vb;
        tin = fmaf(a.x, w1t[0], tin); tin = fmaf(a.y, w1t[1], tin);
        tin = fmaf(a.z, w1t[2], tin); tin = fmaf(a.w, w1t[3], tin);
        tin = fmaf(b.x, w1t[4], tin); tin = fmaf(b.y, w1t[5], tin);
        tin = fmaf(b.z, w1t[6], tin); tin = fmaf(b.w, w1t[7], tin);
        float x2 = tin * tin;
        float z  = tin * fmaf(GELU_B, x2, GELU_A);
        float e2 = __builtin_amdgcn_exp2f(z);
        float r  = __builtin_amdgcn_rcpf(1.0f + e2);
        g = fmaf(wj, fmaf(-tin, r, tin), g);
    }
    float acc = 0.f;
#pragma unroll
    for (int h = 0; h < HID; ++h) {
        float gh = __shfl(g, h, 32);
        acc = fmaf(gh, sW2[h * HID + hid], acc);
    }
    if (valid) out[(size_t)node * HID + hid] = fmaf(ws, sb2[hid], acc) * (1.0f / DEG);
}

extern "C" void kernel_launch(void* const* d_in, const int* in_sizes, int n_in,
                              void* d_out, int out_size, void* d_ws, size_t ws_size,
                              hipStream_t stream) {
    const float* x   = (const float*)d_in[0];
    const float* wq  = (const float*)d_in[1];
    const float* W1  = (const float*)d_in[2];
    const float* b1  = (const float*)d_in[3];
    const float* W2  = (const float*)d_in[4];
    const float* b2  = (const float*)d_in[5];
    const int*   nbr = (const int*)d_in[6];
    float* out = (float*)d_out;

    int N = in_sizes[1];                       // in_weights has N elements
    size_t need = (size_t)N * 64;              // bf16 u table: 64 B per node

    if (ws_size >= need) {
        unsigned* u16 = (unsigned*)d_ws;
        int blocks_pre = (N * 4 + 255) / 256;
        precompute_u16<<<blocks_pre, 256, 0, stream>>>(x, W1, u16, N);
        int blocks_main = (N + 3) / 4;         // 4 nodes (waves) per block
        git_main2<<<blocks_main, 256, 0, stream>>>(u16, x, wq, W1, b1, W2, b2, nbr, out, N);
    } else {
        int blocks = (N + 7) / 8;
        fused_fallback<<<blocks, 256, 0, stream>>>(x, wq, W1, b1, W2, b2, nbr, out, N);
    }
}

// Round 5
// 132.266 us; speedup vs baseline: 1.1040x; 1.1040x over previous
//
#include <hip/hip_runtime.h>

#define DEG 32
#define HID 32
#define CIN 8

typedef float v2f __attribute__((ext_vector_type(2)));

// gelu(x) = x - x * rcp(1 + exp2( x*(A + B*x^2) ))   [jax tanh-approx, refactored]
#define GELU_A ((float)(2.0 * 1.4426950408889634 * 0.7978845608028654))
#define GELU_B ((float)(2.0 * 1.4426950408889634 * 0.7978845608028654 * 0.044715))

__device__ __forceinline__ unsigned f2bf(float f) {   // fp32 -> bf16 (RNE)
    unsigned b = __float_as_uint(f);
    return (b + 0x7fffu + ((b >> 16) & 1u)) >> 16;
}

// Phase 1: u16[n][h] = bf16( x[n] @ W1[:8][h] ).  Row = 64 B = one cache line.
__global__ __launch_bounds__(256) void precompute_u16(
    const float* __restrict__ x, const float* __restrict__ W1,
    unsigned* __restrict__ u16, int N) {
    int tid = blockIdx.x * 256 + threadIdx.x;
    if (tid >= N * 4) return;
    int n = tid >> 2;
    int q = tid & 3;                        // channels q*8 .. q*8+7
    const float4* xp = (const float4*)(x + (size_t)n * CIN);
    float4 a = xp[0], b = xp[1];
    float xv[8] = {a.x, a.y, a.z, a.w, b.x, b.y, b.z, b.w};
    float s[8];
#pragma unroll
    for (int c = 0; c < 8; ++c) s[c] = 0.f;
#pragma unroll
    for (int k = 0; k < 8; ++k) {
        float4 w0 = *(const float4*)(W1 + k * HID + q * 8);
        float4 w1 = *(const float4*)(W1 + k * HID + q * 8 + 4);
        s[0] = fmaf(xv[k], w0.x, s[0]); s[1] = fmaf(xv[k], w0.y, s[1]);
        s[2] = fmaf(xv[k], w0.z, s[2]); s[3] = fmaf(xv[k], w0.w, s[3]);
        s[4] = fmaf(xv[k], w1.x, s[4]); s[5] = fmaf(xv[k], w1.y, s[5]);
        s[6] = fmaf(xv[k], w1.z, s[6]); s[7] = fmaf(xv[k], w1.w, s[7]);
    }
    uint4 o;
    o.x = f2bf(s[0]) | (f2bf(s[1]) << 16);
    o.y = f2bf(s[2]) | (f2bf(s[3]) << 16);
    o.z = f2bf(s[4]) | (f2bf(s[5]) << 16);
    o.w = f2bf(s[6]) | (f2bf(s[7]) << 16);
    *(uint4*)(u16 + (size_t)n * 16 + q * 4) = o;
}

// Phase 2: HALF-WAVE PER NODE (8 nodes / 256-block, R3's coalescing shape).
// Within a half-wave: s = 16-lane group (0/1) handles edges of parity s,
// c2 = lane&15 = channel pair (2c2, 2c2+1) -> packed fp32 gelu.
// Inner: 16 iters, each group reads one full 64B bf16 u-row (16 lanes x 4B,
// perfectly coalesced). ALL 16 loads issued before any compute.
__global__ __launch_bounds__(256) void git_main3(
    const unsigned* __restrict__ u16, const float* __restrict__ x,
    const float* __restrict__ wgt, const float* __restrict__ W1,
    const float* __restrict__ b1, const float* __restrict__ W2,
    const float* __restrict__ b2, const int* __restrict__ nbr,
    float* __restrict__ out, int N) {
    __shared__ float sW2[HID * HID];
    __shared__ float sb2[HID];

    int t = threadIdx.x;
#pragma unroll
    for (int i = 0; i < 4; ++i) sW2[t + i * 256] = W2[t + i * 256];
    if (t < HID) sb2[t] = b2[t];

    int c2   = t & 15;                 // channel pair
    int s    = (t >> 4) & 1;           // edge-parity group within the half-wave
    int slot = t >> 5;                 // node slot 0..7
    int node = blockIdx.x * 8 + slot;
    bool valid = node < N;
    int nc = valid ? node : (N - 1);

    // lane (t&31) owns edge (t&31): id, byte-offset, weight  (coalesced reads)
    int   j_own = nbr[nc * DEG + (t & 31)];
    int   off_l = j_own << 6;                      // bf16 row = 64 bytes
    float w_own = wgt[j_own];                      // 400KB table, cache-hot

    // ws = sum of all 32 neighbor weights (butterfly within the 32-half)
    float ws = w_own;
    ws += __shfl_xor(ws, 1);  ws += __shfl_xor(ws, 2);
    ws += __shfl_xor(ws, 4);  ws += __shfl_xor(ws, 8);
    ws += __shfl_xor(ws, 16);

    // v_i for this lane's channel pair: vb = b1 + x_i @ W1[8:16]  (packed)
    const float4* xip = (const float4*)(x + (size_t)nc * CIN);
    float4 xa = xip[0], xb = xip[1];
    float xs[8] = {xa.x, xa.y, xa.z, xa.w, xb.x, xb.y, xb.z, xb.w};
    v2f vb = *(const v2f*)(b1 + c2 * 2);
#pragma unroll
    for (int k = 0; k < 8; ++k) {
        v2f wcol = *(const v2f*)(W1 + (8 + k) * HID + c2 * 2);
        vb += xs[k] * wcol;
    }

    __syncthreads();   // sW2/sb2 ready (placed here to overlap staging w/ preamble)

    // ---- gather: broadcast offsets/weights, then ALL 16 loads in flight ----
    const char* ub = (const char*)u16;
    int mybyte = c2 * 4;
    unsigned bits[16];
    float    wes[16];
#pragma unroll
    for (int e = 0; e < 16; ++e) {
        int src = 2 * e + s;                        // this group's e-th edge
        int off = __shfl(off_l, src, 32);
        wes[e]  = __shfl(w_own, src, 32);
        bits[e] = *(const unsigned*)(ub + (unsigned)(off + mybyte));
    }

    // ---- packed gelu + weighted accumulate ----
    v2f g = {0.f, 0.f};
#pragma unroll
    for (int e = 0; e < 16; ++e) {
        unsigned bb = bits[e];
        v2f uf;
        uf.x = __uint_as_float(bb << 16);           // channel 2c2
        uf.y = __uint_as_float(bb & 0xffff0000u);   // channel 2c2+1
        v2f tt = uf + vb;
        v2f x2 = tt * tt;
        v2f zz = tt * (x2 * GELU_B + GELU_A);
        v2f ee;
        ee.x = __builtin_amdgcn_exp2f(zz.x);
        ee.y = __builtin_amdgcn_exp2f(zz.y);
        v2f dd = ee + 1.0f;
        v2f rr;
        rr.x = __builtin_amdgcn_rcpf(dd.x);
        rr.y = __builtin_amdgcn_rcpf(dd.y);
        v2f gl = tt - tt * rr;                      // gelu; exact +/-inf limits
        g += wes[e] * gl;
    }

    // combine the two parity groups: lanes differing in bit 4
    g.x += __shfl_xor(g.x, 16);
    g.y += __shfl_xor(g.y, 16);

    // ---- hoisted second linear: acc[o-pair] = sum_h g[h] * W2[h][o-pair] ----
    // h-range split across the two groups (s*16..s*16+15), then reduced.
    v2f acc = {0.f, 0.f};
#pragma unroll
    for (int hh = 0; hh < 16; ++hh) {
        int h = s * 16 + hh;
        int srcl = s * 8 + (hh >> 1);               // lane holding channel h
        float gh = (hh & 1) ? __shfl(g.y, srcl, 32) : __shfl(g.x, srcl, 32);
        v2f wrow = *(const v2f*)(sW2 + h * HID + c2 * 2);  // 2-way bcast, free
        acc += gh * wrow;
    }
    acc.x += __shfl_xor(acc.x, 16);
    acc.y += __shfl_xor(acc.y, 16);

    if (valid && s == 0) {
        v2f bb2 = *(const v2f*)(sb2 + c2 * 2);
        v2f res = (acc + ws * bb2) * (1.0f / DEG);
        *(v2f*)(out + (size_t)node * HID + c2 * 2) = res;   // 128B per node-half
    }
}

// Fallback if d_ws can't hold u16 (needs N*64 bytes): single fused kernel.
__global__ __launch_bounds__(256) void fused_fallback(
    const float* __restrict__ x, const float* __restrict__ wgt,
    const float* __restrict__ W1, const float* __restrict__ b1,
    const float* __restrict__ W2, const float* __restrict__ b2,
    const int* __restrict__ nbr, float* __restrict__ out, int N) {
    __shared__ float sW2[HID * HID];
    __shared__ float sb2[HID];
    __shared__ int2  sp[8 * DEG];
    int t = threadIdx.x;
#pragma unroll
    for (int i = 0; i < 4; ++i) sW2[t + i * 256] = W2[t + i * 256];
    if (t < HID) sb2[t] = b2[t];
    int slot = t >> 5, hid = t & 31;
    int node = blockIdx.x * 8 + slot;
    bool valid = node < N;
    int nc = valid ? node : (N - 1);
    int   j_own = nbr[nc * DEG + hid];
    float w_own = wgt[j_own];
    sp[slot * DEG + hid] = make_int2(j_own * (CIN * 4), __float_as_int(w_own));
    const float4* xip = (const float4*)(x + (size_t)nc * CIN);
    float4 xa = xip[0], xb = xip[1];
    float w1t[8];
#pragma unroll
    for (int k = 0; k < 8; ++k) w1t[k] = W1[k * HID + hid];
    float vb = b1[hid];
    vb = fmaf(xa.x, W1[ 8 * HID + hid], vb);
    vb = fmaf(xa.y, W1[ 9 * HID + hid], vb);
    vb = fmaf(xa.z, W1[10 * HID + hid], vb);
    vb = fmaf(xa.w, W1[11 * HID + hid], vb);
    vb = fmaf(xb.x, W1[12 * HID + hid], vb);
    vb = fmaf(xb.y, W1[13 * HID + hid], vb);
    vb = fmaf(xb.z, W1[14 * HID + hid], vb);
    vb = fmaf(xb.w, W1[15 * HID + hid], vb);
    float ws = w_own;
    ws += __shfl_xor(ws, 1);  ws += __shfl_xor(ws, 2);
    ws += __shfl_xor(ws, 4);  ws += __shfl_xor(ws, 8);
    ws += __shfl_xor(ws, 16);
    __syncthreads();
    const char* xbytes = (const char*)x;
    const int2* myp = &sp[slot * DEG];
    float g = 0.f;
#pragma unroll 8
    for (int e = 0; e < DEG; ++e) {
        int2  p  = myp[e];
        float wj = __int_as_float(p.y);
        const float4* xjp = (const float4*)(xbytes + (unsigned)p.x);
        float4 a = xjp[0], b = xjp[1];
        float tin = vb;
        tin = fmaf(a.x, w1t[0], tin); tin = fmaf(a.y, w1t[1], tin);
        tin = fmaf(a.z, w1t[2], tin); tin = fmaf(a.w, w1t[3], tin);
        tin = fmaf(b.x, w1t[4], tin); tin = fmaf(b.y, w1t[5], tin);
        tin = fmaf(b.z, w1t[6], tin); tin = fmaf(b.w, w1t[7], tin);
        float x2 = tin * tin;
        float z  = tin * fmaf(GELU_B, x2, GELU_A);
        float e2 = __builtin_amdgcn_exp2f(z);
        float r  = __builtin_amdgcn_rcpf(1.0f + e2);
        g = fmaf(wj, fmaf(-tin, r, tin), g);
    }
    float acc = 0.f;
#pragma unroll
    for (int h = 0; h < HID; ++h) {
        float gh = __shfl(g, h, 32);
        acc = fmaf(gh, sW2[h * HID + hid], acc);
    }
    if (valid) out[(size_t)node * HID + hid] = fmaf(ws, sb2[hid], acc) * (1.0f / DEG);
}

extern "C" void kernel_launch(void* const* d_in, const int* in_sizes, int n_in,
                              void* d_out, int out_size, void* d_ws, size_t ws_size,
                              hipStream_t stream) {
    const float* x   = (const float*)d_in[0];
    const float* wq  = (const float*)d_in[1];
    const float* W1  = (const float*)d_in[2];
    const float* b1  = (const float*)d_in[3];
    const float* W2  = (const float*)d_in[4];
    const float* b2  = (const float*)d_in[5];
    const int*   nbr = (const int*)d_in[6];
    float* out = (float*)d_out;

    int N = in_sizes[1];                       // in_weights has N elements
    size_t need = (size_t)N * 64;              // bf16 u table: 64 B per node

    if (ws_size >= need) {
        unsigned* u16 = (unsigned*)d_ws;
        int blocks_pre = (N * 4 + 255) / 256;
        precompute_u16<<<blocks_pre, 256, 0, stream>>>(x, W1, u16, N);
        int blocks_main = (N + 7) / 8;         // 8 nodes per 256-thread block
        git_main3<<<blocks_main, 256, 0, stream>>>(u16, x, wq, W1, b1, W2, b2, nbr, out, N);
    } else {
        int blocks = (N + 7) / 8;
        fused_fallback<<<blocks, 256, 0, stream>>>(x, wq, W1, b1, W2, b2, nbr, out, N);
    }
}